// Round 17
// baseline (5371.227 us; speedup 1.0000x reference)
//
#include <hip/hip_runtime.h>

#define Hs 2048
#define Os 1024
#define NB 256
#define NT 512
#define BSTR 32   // dword stride between go-word slots (128B padding)

typedef unsigned int       uint32;
typedef unsigned long long uint64;
typedef unsigned short     ushort_t;
typedef _Float16 half2v __attribute__((ext_vector_type(2)));

// f32 -> f16 bits (RNE)
__device__ __forceinline__ ushort_t f2h(float f) {
    _Float16 h = (_Float16)f;
    return __builtin_bit_cast(ushort_t, h);
}

// pack two f32 -> f16x2 word
__device__ __forceinline__ uint32 pkh2(float lo, float hi) {
#if __has_builtin(__builtin_amdgcn_cvt_pkrtz)
    return __builtin_bit_cast(uint32, __builtin_amdgcn_cvt_pkrtz(lo, hi));
#else
    return (uint32)f2h(lo) | ((uint32)f2h(hi) << 16);
#endif
}

// f16 pair dot: acc += w[0]*v[0] + w[1]*v[1]  (one v_dot2_f32_f16)
__device__ __forceinline__ float dot2(uint32 wp, uint32 vp, float acc) {
#if __has_builtin(__builtin_amdgcn_fdot2)
    return __builtin_amdgcn_fdot2(__builtin_bit_cast(half2v, wp),
                                  __builtin_bit_cast(half2v, vp), acc, false);
#else
    half2v a = __builtin_bit_cast(half2v, wp), b = __builtin_bit_cast(half2v, vp);
    acc = fmaf((float)a.x, (float)b.x, acc);
    return fmaf((float)a.y, (float)b.y, acc);
#endif
}

__device__ __forceinline__ float dot8(uint4 wq, uint4 vq, float acc) {
    acc = dot2(wq.x, vq.x, acc); acc = dot2(wq.y, vq.y, acc);
    acc = dot2(wq.z, vq.z, acc); acc = dot2(wq.w, vq.w, acc);
    return acc;
}

__device__ __forceinline__ float dot4f(float4 w, float4 v, float acc) {
    acc = fmaf(w.x, v.x, acc); acc = fmaf(w.y, v.y, acc);
    acc = fmaf(w.z, v.z, acc); acc = fmaf(w.w, v.w, acc);
    return acc;
}

// encoder-only LDS swizzle: swap 16B units across 128B blocks
__device__ __forceinline__ int sj(int j) { return j ^ (((j >> 5) & 1) << 2); }

// force 4 dwords to stay materialized in VGPRs (defeats load rematerialization)
#define KEEP4(u) asm volatile("" : "+v"((u).x), "+v"((u).y), "+v"((u).z), "+v"((u).w))

// ---- MALL-coherent relaxed atomics (no cache maintenance) ----
__device__ __forceinline__ uint32 gload(const uint32* p) {
    return __hip_atomic_load(p, __ATOMIC_RELAXED, __HIP_MEMORY_SCOPE_AGENT);
}
__device__ __forceinline__ void gstore(uint32* p, uint32 v) {
    __hip_atomic_store(p, v, __ATOMIC_RELAXED, __HIP_MEMORY_SCOPE_AGENT);
}
__device__ __forceinline__ uint64 gload64(const uint64* p) {
    return __hip_atomic_load(p, __ATOMIC_RELAXED, __HIP_MEMORY_SCOPE_AGENT);
}
__device__ __forceinline__ void gstore64(uint64* p, uint64 v) {
    __hip_atomic_store(p, v, __ATOMIC_RELAXED, __HIP_MEMORY_SCOPE_AGENT);
}
__device__ __forceinline__ uint32 pk_ep(uint64 v)  { return (uint32)(v >> 32); }

// packed partial: {f32 m | f16 s | u16 epoch}   (epoch <= 1025 fits u16)
__device__ __forceinline__ uint64 pack_ms(float m, float s, uint32 ep) {
    return ((uint64)__float_as_uint(m) << 32) | ((uint64)f2h(s) << 16) | (uint64)(ep & 0xffffu);
}
__device__ __forceinline__ uint32 ms_ep(uint64 v) { return (uint32)(v & 0xffffu); }
__device__ __forceinline__ float  ms_m(uint64 v)  { return __uint_as_float((uint32)(v >> 32)); }
__device__ __forceinline__ float  ms_s(uint64 v)  {
    ushort_t b = (ushort_t)(v >> 16);
    return (float)__builtin_bit_cast(_Float16, b);
}
__device__ __forceinline__ uint64 spin_ms(const uint64* p, uint32 target) {
    uint64 v = gload64(p);
    while (ms_ep(v) < target) { __builtin_amdgcn_s_sleep(0); v = gload64(p); }
    return v;
}

// ---- prep: f32 -> f16 (as ushort) ----
__global__ void cvt_kernel(const float* __restrict__ src, ushort_t* __restrict__ dst, int n4) {
    int stride = gridDim.x * blockDim.x;
    for (int idx = blockIdx.x * blockDim.x + threadIdx.x; idx < n4; idx += stride) {
        float4 f = ((const float4*)src)[idx];
        ushort4 o;
        o.x = f2h(f.x); o.y = f2h(f.y); o.z = f2h(f.z); o.w = f2h(f.w);
        ((ushort4*)dst)[idx] = o;
    }
}

// ---- persistent cooperative decode: R15 skeleton + batched-retry detect ----
__global__ void __launch_bounds__(NT) decode_kernel(
    const float* __restrict__ a,
    const float* __restrict__ encWih,
    const float* __restrict__ encBih,
    const float* __restrict__ encBhh,
    const float* __restrict__ intoW,
    const float* __restrict__ intoB,
    const float* __restrict__ decBih,
    const float* __restrict__ decBhh,
    const float* __restrict__ outB,
    const ushort_t* __restrict__ Wih,   // f16 [3H][H]
    const ushort_t* __restrict__ Whh,   // f16 [3H][H]
    const ushort_t* __restrict__ Wout,  // f16 [O][H]
    uint64* __restrict__ hpk,           // [H/2] tagged {f16x2 pair, epoch}, memset 0
    uint64* __restrict__ pm,            // [NB] packed {m,s,epoch}, memset 0
    uint32* __restrict__ go,            // [8*BSTR] go words, memset 0
    float* __restrict__ out)            // [O]
{
    const int tid  = threadIdx.x;
    const int b    = blockIdx.x;
    const int lane = tid & 63;
    const int w    = tid >> 6;
    const int i    = b * 8 + w;   // this wave's h element (0..2047)

    __shared__ __align__(16) float  h_enc[Hs];      // encoder staging only
    __shared__ __align__(16) uint32 h16[Hs / 2];    // h as f16 pairs
    __shared__ __align__(16) uint32 v16[Hs / 2];    // v as f16 pairs
    __shared__ float red_a[8];
    __shared__ float h_sh[8];                       // f32 h staging for pair-pack
    __shared__ float xshare;

    // hoisted loop invariants
    const float bxr = decBih[i], bxz = decBih[i + Hs], bxn = decBih[i + 2 * Hs];
    const float bhr = decBhh[i], bhz = decBhh[i + Hs], bhn = decBhh[i + 2 * Hs];
    const float4 iw4 = ((const float4*)intoW)[tid];   // elems 4*tid..4*tid+3
    const float4 ib4 = ((const float4*)intoB)[tid];
    const float ob0 = outB[b * 4 + 0], ob1 = outB[b * 4 + 1], ob2 = outB[b * 4 + 2], ob3 = outB[b * 4 + 3];

    const ushort_t* Xr = Wih + (size_t)i * Hs;
    const ushort_t* Xz = Wih + (size_t)(i + Hs) * Hs;
    const ushort_t* Xn = Wih + (size_t)(i + 2 * Hs) * Hs;
    const ushort_t* Hr = Whh + (size_t)i * Hs;
    const ushort_t* Hz = Whh + (size_t)(i + Hs) * Hs;
    const ushort_t* Hn = Whh + (size_t)(i + 2 * Hs) * Hs;

    float hold;   // this wave's OWN h[i], exact f32, carried in-register

    // ===== encoder: h0 = GRUcell(a, h=0)  (gh = enc_bhh since Whh@0 = 0) =====
    for (int k = tid; k < Hs; k += NT) h_enc[sj(k)] = a[k];
    __syncthreads();
    {
        float sr = 0.f, sz = 0.f, sn = 0.f;
        const float* Rr = encWih + (size_t)i * Hs;
        const float* Rz = encWih + (size_t)(i + Hs) * Hs;
        const float* Rn = encWih + (size_t)(i + 2 * Hs) * Hs;
#pragma unroll
        for (int it = 0; it < 4; ++it) {
            int j0 = it * 512 + lane * 8;
            float4 a0 = *(const float4*)(h_enc + sj(j0));
            float4 a1 = *(const float4*)(h_enc + sj(j0 + 4));
            sr = dot4f(*(const float4*)(Rr + j0), a0, sr);
            sr = dot4f(*(const float4*)(Rr + j0 + 4), a1, sr);
            sz = dot4f(*(const float4*)(Rz + j0), a0, sz);
            sz = dot4f(*(const float4*)(Rz + j0 + 4), a1, sz);
            sn = dot4f(*(const float4*)(Rn + j0), a0, sn);
            sn = dot4f(*(const float4*)(Rn + j0 + 4), a1, sn);
        }
#pragma unroll
        for (int m = 1; m < 64; m <<= 1) {
            sr += __shfl_xor(sr, m, 64);
            sz += __shfl_xor(sz, m, 64);
            sn += __shfl_xor(sn, m, 64);
        }
        float gxr = sr + encBih[i];
        float gxz = sz + encBih[i + Hs];
        float gxn = sn + encBih[i + 2 * Hs];
        float r = 1.f / (1.f + __expf(-(gxr + encBhh[i])));
        float z = 1.f / (1.f + __expf(-(gxz + encBhh[i + Hs])));
        float n = tanhf(gxn + r * encBhh[i + 2 * Hs]);
        hold = (1.f - z) * n;                 // h0[i] in-register
        if (lane == 0) h_sh[w] = hold;
    }

    // ===== hoist decoder weights into registers (f16 pairs, 26 uint4 = 104 VGPR) =====
    uint4 wXr[4], wXz[4], wXn[4], wHr[4], wHz[4], wHn[4], wO[2];
    {
        const ushort_t* R = Wout + (size_t)(b * 4 + (w >> 1)) * Hs + (w & 1) * 1024;
#pragma unroll
        for (int it = 0; it < 4; ++it) {
            int j0 = it * 512 + lane * 8;
            wXr[it] = *(const uint4*)(Xr + j0);
            wXz[it] = *(const uint4*)(Xz + j0);
            wXn[it] = *(const uint4*)(Xn + j0);
            wHr[it] = *(const uint4*)(Hr + j0);
            wHz[it] = *(const uint4*)(Hz + j0);
            wHn[it] = *(const uint4*)(Hn + j0);
        }
#pragma unroll
        for (int it = 0; it < 2; ++it)
            wO[it] = *(const uint4*)(R + it * 512 + lane * 8);
    }

    // ===== h0 sync (epoch 1): publish, batched-retry detect, consume AFTER go =====
    __syncthreads();   // h_sh complete
    if (tid < 4) {
        uint32 pr = pkh2(h_sh[2 * tid], h_sh[2 * tid + 1]);
        gstore64(hpk + b * 4 + tid, (uint64)pr | (1ull << 32));
    }
    if (b == 0) {
        if (tid < 64) {
            uint64 va[16];
#pragma unroll
            for (int k = 0; k < 16; ++k) va[k] = gload64(hpk + tid + k * 64);
            bool pend = true;
            while (pend) {
                pend = false;
#pragma unroll
                for (int k = 0; k < 16; ++k)
                    if (pk_ep(va[k]) < 1u) { pend = true; va[k] = gload64(hpk + tid + k * 64); }
                if (pend) __builtin_amdgcn_s_sleep(0);
            }
            if (tid < 8) gstore(go + tid * BSTR, 1u);
#pragma unroll
            for (int k = 0; k < 16; ++k) h16[tid + k * 64] = (uint32)va[k];
        }
        __syncthreads();
    } else {
        if (tid == 0) {
            const uint32* g = go + (b & 7) * BSTR;
            while (gload(g) < 1u) __builtin_amdgcn_s_sleep(0);
        }
        __syncthreads();   // go seen: all tags >= 1 at MALL; loads AFTER gate
        uint64 p0 = gload64(hpk + tid);
        uint64 p1 = gload64(hpk + tid + 512);
        h16[tid]       = (uint32)p0;
        h16[tid + 512] = (uint32)p1;
        __syncthreads();
    }

    for (int t = 0; t < Os; ++t) {
        const uint32 eph = (uint32)t + 2u;   // epoch of h(t+1)

        // keep-alive: force the weight registers live across the loop backedge
        KEEP4(wXr[0]); KEEP4(wXr[1]); KEEP4(wXr[2]); KEEP4(wXr[3]);
        KEEP4(wXz[0]); KEEP4(wXz[1]); KEEP4(wXz[2]); KEEP4(wXz[3]);
        KEEP4(wXn[0]); KEEP4(wXn[1]); KEEP4(wXn[2]); KEEP4(wXn[3]);
        KEEP4(wHr[0]); KEEP4(wHr[1]); KEEP4(wHr[2]); KEEP4(wHr[3]);
        KEEP4(wHz[0]); KEEP4(wHz[1]); KEEP4(wHz[2]); KEEP4(wHz[3]);
        KEEP4(wHn[0]); KEEP4(wHn[1]); KEEP4(wHn[2]); KEEP4(wHn[3]);
        KEEP4(wO[0]);  KEEP4(wO[1]);

        // (1) gh = Whh @ h(t)  -- f16-pair dot2 from LDS h16
        float ahr = 0.f, ahz = 0.f, ahn = 0.f;
#pragma unroll
        for (int it = 0; it < 4; ++it) {
            const uint4 hq = *(const uint4*)(h16 + it * 256 + lane * 4);
            ahr = dot8(wHr[it], hq, ahr);
            ahz = dot8(wHz[it], hq, ahz);
            ahn = dot8(wHn[it], hq, ahn);
        }
#pragma unroll
        for (int m = 1; m < 64; m <<= 1) {
            ahr += __shfl_xor(ahr, m, 64);
            ahz += __shfl_xor(ahz, m, 64);
            ahn += __shfl_xor(ahn, m, 64);
        }

        // (2) wave 0: gather 256 packed partials (tag t), batched retry
        if (w == 0) {
            if (t > 0) {
                const uint32 tg = (uint32)t;
                uint64 v0 = gload64(pm + lane);
                uint64 v1 = gload64(pm + lane + 64);
                uint64 v2 = gload64(pm + lane + 128);
                uint64 v3 = gload64(pm + lane + 192);
                bool pend = true;
                while (pend) {
                    pend = false;
                    if (ms_ep(v0) < tg) { pend = true; v0 = gload64(pm + lane); }
                    if (ms_ep(v1) < tg) { pend = true; v1 = gload64(pm + lane + 64); }
                    if (ms_ep(v2) < tg) { pend = true; v2 = gload64(pm + lane + 128); }
                    if (ms_ep(v3) < tg) { pend = true; v3 = gload64(pm + lane + 192); }
                    if (pend) __builtin_amdgcn_s_sleep(0);
                }
                float xm = ms_m(v0), xs = ms_s(v0);
                {
                    float mo = ms_m(v1), so = ms_s(v1);
                    float M = fmaxf(xm, mo);
                    xs = xs * __expf(xm - M) + so * __expf(mo - M); xm = M;
                }
                {
                    float mo = ms_m(v2), so = ms_s(v2);
                    float M = fmaxf(xm, mo);
                    xs = xs * __expf(xm - M) + so * __expf(mo - M); xm = M;
                }
                {
                    float mo = ms_m(v3), so = ms_s(v3);
                    float M = fmaxf(xm, mo);
                    xs = xs * __expf(xm - M) + so * __expf(mo - M); xm = M;
                }
#pragma unroll
                for (int k = 1; k < 64; k <<= 1) {
                    float mo = __shfl_xor(xm, k, 64);
                    float so = __shfl_xor(xs, k, 64);
                    float M = fmaxf(xm, mo);
                    xs = xs * __expf(xm - M) + so * __expf(mo - M);
                    xm = M;
                }
                if (lane == 0) {
                    float xv = -__logf(xs);
                    xshare = xv;
                    if (b == 0) out[t - 1] = xv;
                }
            } else if (lane == 0) {
                xshare = 0.f;
            }
        }
        __syncthreads();
        const float x = xshare;

        // (3) v = LeakyReLU(intoW*x + intoB) -> LDS as f16 pairs
        {
            float v0 = fmaf(iw4.x, x, ib4.x); v0 = (v0 > 0.f) ? v0 : 0.01f * v0;
            float v1 = fmaf(iw4.y, x, ib4.y); v1 = (v1 > 0.f) ? v1 : 0.01f * v1;
            float v2 = fmaf(iw4.z, x, ib4.z); v2 = (v2 > 0.f) ? v2 : 0.01f * v2;
            float v3 = fmaf(iw4.w, x, ib4.w); v3 = (v3 > 0.f) ? v3 : 0.01f * v3;
            v16[2 * tid]     = pkh2(v0, v1);
            v16[2 * tid + 1] = pkh2(v2, v3);
        }
        __syncthreads();

        // (4) gx = Wih @ v; combine -> h(t+1)[i]; stage to LDS
        {
            float axr = 0.f, axz = 0.f, axn = 0.f;
#pragma unroll
            for (int it = 0; it < 4; ++it) {
                const uint4 vq = *(const uint4*)(v16 + it * 256 + lane * 4);
                axr = dot8(wXr[it], vq, axr);
                axz = dot8(wXz[it], vq, axz);
                axn = dot8(wXn[it], vq, axn);
            }
#pragma unroll
            for (int m = 1; m < 64; m <<= 1) {
                axr += __shfl_xor(axr, m, 64);
                axz += __shfl_xor(axz, m, 64);
                axn += __shfl_xor(axn, m, 64);
            }
            float r = 1.f / (1.f + __expf(-(axr + bxr + ahr + bhr)));
            float z = 1.f / (1.f + __expf(-(axz + bxz + ahz + bhz)));
            float n = tanhf(axn + bxn + r * (ahn + bhn));
            float hn = (1.f - z) * n + z * hold;
            hold = hn;                        // keep own h exact for next step
            if (lane == 0) h_sh[w] = hn;
        }
        __syncthreads();

        // (4b) publish tagged h pairs (4 per block) -- the store IS the arrival
        if (tid < 4) {
            uint32 pr = pkh2(h_sh[2 * tid], h_sh[2 * tid + 1]);
            gstore64(hpk + b * 4 + tid, (uint64)pr | ((uint64)eph << 32));
        }

        // (5)+(6) h-sync: batched-retry detect (block 0), consume AFTER gate
        if (b == 0) {
            if (tid < 64) {   // aggregator wave: poll all 1024 words, release, fill h16
                uint64 va[16];
#pragma unroll
                for (int k = 0; k < 16; ++k) va[k] = gload64(hpk + tid + k * 64);
                bool pend = true;
                while (pend) {
                    pend = false;
#pragma unroll
                    for (int k = 0; k < 16; ++k)
                        if (pk_ep(va[k]) < eph) { pend = true; va[k] = gload64(hpk + tid + k * 64); }
                    if (pend) __builtin_amdgcn_s_sleep(0);
                }
                if (tid < 8) gstore(go + tid * BSTR, eph);
#pragma unroll
                for (int k = 0; k < 16; ++k) h16[tid + k * 64] = (uint32)va[k];
            }
            __syncthreads();
        } else {
            if (tid == 0) {
                const uint32* g = go + (b & 7) * BSTR;
                while (gload(g) < eph) __builtin_amdgcn_s_sleep(0);
            }
            __syncthreads();   // go seen: all tags >= eph at MALL
            uint64 p0 = gload64(hpk + tid);
            uint64 p1 = gload64(hpk + tid + 512);
            h16[tid]       = (uint32)p0;
            h16[tid + 512] = (uint32)p1;
            __syncthreads();
        }

        // (7) logits partials on h(t+1) (f16 wO); publish packed tag t+1
        {
            const int jbp = (w & 1) * 512;   // pair offset
            float acc = 0.f;
#pragma unroll
            for (int it = 0; it < 2; ++it) {
                const uint4 hq = *(const uint4*)(h16 + jbp + it * 256 + lane * 4);
                acc = dot8(wO[it], hq, acc);
            }
#pragma unroll
            for (int m = 1; m < 64; m <<= 1) acc += __shfl_xor(acc, m, 64);
            if (lane == 0) red_a[w] = acc;
            __syncthreads();
            if (tid == 0) {
                float l0 = red_a[0] + red_a[1] + ob0;
                float l1 = red_a[2] + red_a[3] + ob1;
                float l2 = red_a[4] + red_a[5] + ob2;
                float l3 = red_a[6] + red_a[7] + ob3;
                float m = fmaxf(fmaxf(l0, l1), fmaxf(l2, l3));
                float s = __expf(l0 - m) + __expf(l1 - m) + __expf(l2 - m) + __expf(l3 - m);
                gstore64(pm + b, pack_ms(m, s, (uint32)(t + 1)));
            }
        }
        // no loop-end sync: (5)/(6) syncs already order red_a/v16/xshare reuse
    }

    // epilogue: out[Os-1] from the last published partials (tag Os)
    if (b == 0 && w == 0) {
        float xm = -1e30f, xs = 0.f;
#pragma unroll
        for (int q = 0; q < 4; ++q) {
            uint64 v = spin_ms(pm + lane + q * 64, (uint32)Os);
            float mo = ms_m(v), so = ms_s(v);
            float M = fmaxf(xm, mo);
            xs = xs * __expf(xm - M) + so * __expf(mo - M);
            xm = M;
        }
#pragma unroll
        for (int k = 1; k < 64; k <<= 1) {
            float mo = __shfl_xor(xm, k, 64);
            float so = __shfl_xor(xs, k, 64);
            float M = fmaxf(xm, mo);
            xs = xs * __expf(xm - M) + so * __expf(mo - M);
            xm = M;
        }
        if (lane == 0) out[Os - 1] = -__logf(xs);
    }
}

extern "C" void kernel_launch(void* const* d_in, const int* in_sizes, int n_in,
                              void* d_out, int out_size, void* d_ws, size_t ws_size,
                              hipStream_t stream) {
    const float* a      = (const float*)d_in[0];
    const float* encWih = (const float*)d_in[1];
    // d_in[2] enc_Whh unused (h0 = 0)
    const float* encBih = (const float*)d_in[3];
    const float* encBhh = (const float*)d_in[4];
    const float* intoW  = (const float*)d_in[5];
    const float* intoB  = (const float*)d_in[6];
    const float* decWih = (const float*)d_in[7];
    const float* decWhh = (const float*)d_in[8];
    const float* decBih = (const float*)d_in[9];
    const float* decBhh = (const float*)d_in[10];
    const float* outW   = (const float*)d_in[11];
    const float* outB   = (const float*)d_in[12];

    ushort_t* wsWih  = (ushort_t*)d_ws;
    ushort_t* wsWhh  = wsWih + (size_t)3 * Hs * Hs;
    ushort_t* wsWout = wsWhh + (size_t)3 * Hs * Hs;
    uint64*   hpk    = (uint64*)(wsWout + (size_t)Os * Hs);
    uint64*   pmw    = hpk + Hs / 2;
    uint32*   gow    = (uint32*)(pmw + NB);
    float*    out    = (float*)d_out;

    cvt_kernel<<<4096, 256, 0, stream>>>(decWih, wsWih, 3 * Hs * Hs / 4);
    cvt_kernel<<<4096, 256, 0, stream>>>(decWhh, wsWhh, 3 * Hs * Hs / 4);
    cvt_kernel<<<1024, 256, 0, stream>>>(outW,  wsWout, Os * Hs / 4);
    // reset all epoch-tagged words + go words (contiguous)
    hipMemsetAsync(hpk, 0, (Hs / 2 + NB) * sizeof(uint64) + 8 * BSTR * sizeof(uint32), stream);

    void* args[] = {
        (void*)&a, (void*)&encWih, (void*)&encBih, (void*)&encBhh,
        (void*)&intoW, (void*)&intoB, (void*)&decBih, (void*)&decBhh,
        (void*)&outB, (void*)&wsWih, (void*)&wsWhh, (void*)&wsWout,
        (void*)&hpk, (void*)&pmw, (void*)&gow, (void*)&out
    };
    hipLaunchCooperativeKernel(reinterpret_cast<void*>(decode_kernel),
                               dim3(NB), dim3(NT), args, 0, stream);
}

// Round 18
// 4712.245 us; speedup vs baseline: 1.1398x; 1.1398x over previous
//
#include <hip/hip_runtime.h>

#define Hs 2048
#define Os 1024
#define NB 256
#define NT 512
#define BSTR 32   // dword stride between go-word slots (128B padding)

typedef unsigned int       uint32;
typedef unsigned long long uint64;
typedef unsigned short     ushort_t;
typedef _Float16 half2v __attribute__((ext_vector_type(2)));

// f32 -> f16 bits (RNE)
__device__ __forceinline__ ushort_t f2h(float f) {
    _Float16 h = (_Float16)f;
    return __builtin_bit_cast(ushort_t, h);
}

// pack two f32 -> f16x2 word
__device__ __forceinline__ uint32 pkh2(float lo, float hi) {
#if __has_builtin(__builtin_amdgcn_cvt_pkrtz)
    return __builtin_bit_cast(uint32, __builtin_amdgcn_cvt_pkrtz(lo, hi));
#else
    return (uint32)f2h(lo) | ((uint32)f2h(hi) << 16);
#endif
}

// f16 pair dot: acc += w[0]*v[0] + w[1]*v[1]  (one v_dot2_f32_f16)
__device__ __forceinline__ float dot2(uint32 wp, uint32 vp, float acc) {
#if __has_builtin(__builtin_amdgcn_fdot2)
    return __builtin_amdgcn_fdot2(__builtin_bit_cast(half2v, wp),
                                  __builtin_bit_cast(half2v, vp), acc, false);
#else
    half2v a = __builtin_bit_cast(half2v, wp), b = __builtin_bit_cast(half2v, vp);
    acc = fmaf((float)a.x, (float)b.x, acc);
    return fmaf((float)a.y, (float)b.y, acc);
#endif
}

__device__ __forceinline__ float dot8(uint4 wq, uint4 vq, float acc) {
    acc = dot2(wq.x, vq.x, acc); acc = dot2(wq.y, vq.y, acc);
    acc = dot2(wq.z, vq.z, acc); acc = dot2(wq.w, vq.w, acc);
    return acc;
}

__device__ __forceinline__ float dot4f(float4 w, float4 v, float acc) {
    acc = fmaf(w.x, v.x, acc); acc = fmaf(w.y, v.y, acc);
    acc = fmaf(w.z, v.z, acc); acc = fmaf(w.w, v.w, acc);
    return acc;
}

// encoder-only LDS swizzle: swap 16B units across 128B blocks
__device__ __forceinline__ int sj(int j) { return j ^ (((j >> 5) & 1) << 2); }

// force 4 dwords to stay materialized in VGPRs (defeats load rematerialization)
#define KEEP4(u) asm volatile("" : "+v"((u).x), "+v"((u).y), "+v"((u).z), "+v"((u).w))

// ---- MALL-coherent relaxed atomics (no cache maintenance) ----
__device__ __forceinline__ uint32 gload(const uint32* p) {
    return __hip_atomic_load(p, __ATOMIC_RELAXED, __HIP_MEMORY_SCOPE_AGENT);
}
__device__ __forceinline__ void gstore(uint32* p, uint32 v) {
    __hip_atomic_store(p, v, __ATOMIC_RELAXED, __HIP_MEMORY_SCOPE_AGENT);
}
__device__ __forceinline__ uint64 gload64(const uint64* p) {
    return __hip_atomic_load(p, __ATOMIC_RELAXED, __HIP_MEMORY_SCOPE_AGENT);
}
__device__ __forceinline__ void gstore64(uint64* p, uint64 v) {
    __hip_atomic_store(p, v, __ATOMIC_RELAXED, __HIP_MEMORY_SCOPE_AGENT);
}
__device__ __forceinline__ uint32 pk_ep(uint64 v)  { return (uint32)(v >> 32); }

// packed partial: {f32 m | f16 s | u16 epoch}   (epoch <= 1025 fits u16)
__device__ __forceinline__ uint64 pack_ms(float m, float s, uint32 ep) {
    return ((uint64)__float_as_uint(m) << 32) | ((uint64)f2h(s) << 16) | (uint64)(ep & 0xffffu);
}
__device__ __forceinline__ uint32 ms_ep(uint64 v) { return (uint32)(v & 0xffffu); }
__device__ __forceinline__ float  ms_m(uint64 v)  { return __uint_as_float((uint32)(v >> 32)); }
__device__ __forceinline__ float  ms_s(uint64 v)  {
    ushort_t b = (ushort_t)(v >> 16);
    return (float)__builtin_bit_cast(_Float16, b);
}
__device__ __forceinline__ uint64 spin_ms(const uint64* p, uint32 target) {
    uint64 v = gload64(p);
    while (ms_ep(v) < target) { __builtin_amdgcn_s_sleep(0); v = gload64(p); }
    return v;
}

// ---- prep: f32 -> f16 (as ushort) ----
__global__ void cvt_kernel(const float* __restrict__ src, ushort_t* __restrict__ dst, int n4) {
    int stride = gridDim.x * blockDim.x;
    for (int idx = blockIdx.x * blockDim.x + threadIdx.x; idx < n4; idx += stride) {
        float4 f = ((const float4*)src)[idx];
        ushort4 o;
        o.x = f2h(f.x); o.y = f2h(f.y); o.z = f2h(f.z); o.w = f2h(f.w);
        ((ushort4*)dst)[idx] = o;
    }
}

// ---- persistent cooperative decode: R12 skeleton + packed partials (best: R15) ----
__global__ void __launch_bounds__(NT) decode_kernel(
    const float* __restrict__ a,
    const float* __restrict__ encWih,
    const float* __restrict__ encBih,
    const float* __restrict__ encBhh,
    const float* __restrict__ intoW,
    const float* __restrict__ intoB,
    const float* __restrict__ decBih,
    const float* __restrict__ decBhh,
    const float* __restrict__ outB,
    const ushort_t* __restrict__ Wih,   // f16 [3H][H]
    const ushort_t* __restrict__ Whh,   // f16 [3H][H]
    const ushort_t* __restrict__ Wout,  // f16 [O][H]
    uint64* __restrict__ hpk,           // [H/2] tagged {f16x2 pair, epoch}, memset 0
    uint64* __restrict__ pm,            // [NB] packed {m,s,epoch}, memset 0
    uint32* __restrict__ go,            // [8*BSTR] go words, memset 0
    float* __restrict__ out)            // [O]
{
    const int tid  = threadIdx.x;
    const int b    = blockIdx.x;
    const int lane = tid & 63;
    const int w    = tid >> 6;
    const int i    = b * 8 + w;   // this wave's h element (0..2047)

    __shared__ __align__(16) float  h_enc[Hs];      // encoder staging only
    __shared__ __align__(16) uint32 h16[Hs / 2];    // h as f16 pairs
    __shared__ __align__(16) uint32 v16[Hs / 2];    // v as f16 pairs
    __shared__ float red_a[8];
    __shared__ float h_sh[8];                       // f32 h staging for pair-pack
    __shared__ float xshare;

    // hoisted loop invariants
    const float bxr = decBih[i], bxz = decBih[i + Hs], bxn = decBih[i + 2 * Hs];
    const float bhr = decBhh[i], bhz = decBhh[i + Hs], bhn = decBhh[i + 2 * Hs];
    const float4 iw4 = ((const float4*)intoW)[tid];   // elems 4*tid..4*tid+3
    const float4 ib4 = ((const float4*)intoB)[tid];
    const float ob0 = outB[b * 4 + 0], ob1 = outB[b * 4 + 1], ob2 = outB[b * 4 + 2], ob3 = outB[b * 4 + 3];

    const ushort_t* Xr = Wih + (size_t)i * Hs;
    const ushort_t* Xz = Wih + (size_t)(i + Hs) * Hs;
    const ushort_t* Xn = Wih + (size_t)(i + 2 * Hs) * Hs;
    const ushort_t* Hr = Whh + (size_t)i * Hs;
    const ushort_t* Hz = Whh + (size_t)(i + Hs) * Hs;
    const ushort_t* Hn = Whh + (size_t)(i + 2 * Hs) * Hs;

    float hold;   // this wave's OWN h[i], exact f32, carried in-register

    // ===== encoder: h0 = GRUcell(a, h=0)  (gh = enc_bhh since Whh@0 = 0) =====
    for (int k = tid; k < Hs; k += NT) h_enc[sj(k)] = a[k];
    __syncthreads();
    {
        float sr = 0.f, sz = 0.f, sn = 0.f;
        const float* Rr = encWih + (size_t)i * Hs;
        const float* Rz = encWih + (size_t)(i + Hs) * Hs;
        const float* Rn = encWih + (size_t)(i + 2 * Hs) * Hs;
#pragma unroll
        for (int it = 0; it < 4; ++it) {
            int j0 = it * 512 + lane * 8;
            float4 a0 = *(const float4*)(h_enc + sj(j0));
            float4 a1 = *(const float4*)(h_enc + sj(j0 + 4));
            sr = dot4f(*(const float4*)(Rr + j0), a0, sr);
            sr = dot4f(*(const float4*)(Rr + j0 + 4), a1, sr);
            sz = dot4f(*(const float4*)(Rz + j0), a0, sz);
            sz = dot4f(*(const float4*)(Rz + j0 + 4), a1, sz);
            sn = dot4f(*(const float4*)(Rn + j0), a0, sn);
            sn = dot4f(*(const float4*)(Rn + j0 + 4), a1, sn);
        }
#pragma unroll
        for (int m = 1; m < 64; m <<= 1) {
            sr += __shfl_xor(sr, m, 64);
            sz += __shfl_xor(sz, m, 64);
            sn += __shfl_xor(sn, m, 64);
        }
        float gxr = sr + encBih[i];
        float gxz = sz + encBih[i + Hs];
        float gxn = sn + encBih[i + 2 * Hs];
        float r = 1.f / (1.f + __expf(-(gxr + encBhh[i])));
        float z = 1.f / (1.f + __expf(-(gxz + encBhh[i + Hs])));
        float n = tanhf(gxn + r * encBhh[i + 2 * Hs]);
        hold = (1.f - z) * n;                 // h0[i] in-register
        if (lane == 0) h_sh[w] = hold;
    }

    // ===== hoist decoder weights into registers (f16 pairs, 26 uint4 = 104 VGPR) =====
    uint4 wXr[4], wXz[4], wXn[4], wHr[4], wHz[4], wHn[4], wO[2];
    {
        const ushort_t* R = Wout + (size_t)(b * 4 + (w >> 1)) * Hs + (w & 1) * 1024;
#pragma unroll
        for (int it = 0; it < 4; ++it) {
            int j0 = it * 512 + lane * 8;
            wXr[it] = *(const uint4*)(Xr + j0);
            wXz[it] = *(const uint4*)(Xz + j0);
            wXn[it] = *(const uint4*)(Xn + j0);
            wHr[it] = *(const uint4*)(Hr + j0);
            wHz[it] = *(const uint4*)(Hz + j0);
            wHn[it] = *(const uint4*)(Hn + j0);
        }
#pragma unroll
        for (int it = 0; it < 2; ++it)
            wO[it] = *(const uint4*)(R + it * 512 + lane * 8);
    }

    // ===== h0 sync (epoch 1): publish tagged pairs, release, consume AFTER go =====
    __syncthreads();   // h_sh complete
    if (tid < 4) {
        uint32 pr = pkh2(h_sh[2 * tid], h_sh[2 * tid + 1]);
        gstore64(hpk + b * 4 + tid, (uint64)pr | (1ull << 32));
    }
    if (b == 0) {
        if (tid < 64) {
            uint64 va[16];
#pragma unroll
            for (int k = 0; k < 16; ++k) va[k] = gload64(hpk + tid + k * 64);
#pragma unroll
            for (int k = 0; k < 16; ++k)
                while (pk_ep(va[k]) < 1u) { __builtin_amdgcn_s_sleep(0); va[k] = gload64(hpk + tid + k * 64); }
            if (tid < 8) gstore(go + tid * BSTR, 1u);
#pragma unroll
            for (int k = 0; k < 16; ++k) h16[tid + k * 64] = (uint32)va[k];
        }
        __syncthreads();
    } else {
        if (tid == 0) {
            const uint32* g = go + (b & 7) * BSTR;
            while (gload(g) < 1u) __builtin_amdgcn_s_sleep(0);
        }
        __syncthreads();   // go seen: all tags >= 1 at MALL; loads AFTER gate
        uint64 p0 = gload64(hpk + tid);
        uint64 p1 = gload64(hpk + tid + 512);
        h16[tid]       = (uint32)p0;
        h16[tid + 512] = (uint32)p1;
        __syncthreads();
    }

    for (int t = 0; t < Os; ++t) {
        const uint32 eph = (uint32)t + 2u;   // epoch of h(t+1)

        // keep-alive: force the weight registers live across the loop backedge
        KEEP4(wXr[0]); KEEP4(wXr[1]); KEEP4(wXr[2]); KEEP4(wXr[3]);
        KEEP4(wXz[0]); KEEP4(wXz[1]); KEEP4(wXz[2]); KEEP4(wXz[3]);
        KEEP4(wXn[0]); KEEP4(wXn[1]); KEEP4(wXn[2]); KEEP4(wXn[3]);
        KEEP4(wHr[0]); KEEP4(wHr[1]); KEEP4(wHr[2]); KEEP4(wHr[3]);
        KEEP4(wHz[0]); KEEP4(wHz[1]); KEEP4(wHz[2]); KEEP4(wHz[3]);
        KEEP4(wHn[0]); KEEP4(wHn[1]); KEEP4(wHn[2]); KEEP4(wHn[3]);
        KEEP4(wO[0]);  KEEP4(wO[1]);

        // (1) gh = Whh @ h(t)  -- f16-pair dot2 from LDS h16
        float ahr = 0.f, ahz = 0.f, ahn = 0.f;
#pragma unroll
        for (int it = 0; it < 4; ++it) {
            const uint4 hq = *(const uint4*)(h16 + it * 256 + lane * 4);
            ahr = dot8(wHr[it], hq, ahr);
            ahz = dot8(wHz[it], hq, ahz);
            ahn = dot8(wHn[it], hq, ahn);
        }
#pragma unroll
        for (int m = 1; m < 64; m <<= 1) {
            ahr += __shfl_xor(ahr, m, 64);
            ahz += __shfl_xor(ahz, m, 64);
            ahn += __shfl_xor(ahn, m, 64);
        }

        // (2) wave 0: gather 256 packed partials (tag t) -> x ; batch-issue then retry
        if (w == 0) {
            if (t > 0) {
                const uint32 tg = (uint32)t;
                const uint64 *q0 = pm + lane,       *q1 = pm + lane + 64,
                             *q2 = pm + lane + 128, *q3 = pm + lane + 192;
                uint64 v0 = gload64(q0), v1 = gload64(q1), v2 = gload64(q2), v3 = gload64(q3);
                while (ms_ep(v0) < tg) { __builtin_amdgcn_s_sleep(0); v0 = gload64(q0); }
                while (ms_ep(v1) < tg) { __builtin_amdgcn_s_sleep(0); v1 = gload64(q1); }
                while (ms_ep(v2) < tg) { __builtin_amdgcn_s_sleep(0); v2 = gload64(q2); }
                while (ms_ep(v3) < tg) { __builtin_amdgcn_s_sleep(0); v3 = gload64(q3); }
                float xm = ms_m(v0), xs = ms_s(v0);
                {
                    float mo = ms_m(v1), so = ms_s(v1);
                    float M = fmaxf(xm, mo);
                    xs = xs * __expf(xm - M) + so * __expf(mo - M); xm = M;
                }
                {
                    float mo = ms_m(v2), so = ms_s(v2);
                    float M = fmaxf(xm, mo);
                    xs = xs * __expf(xm - M) + so * __expf(mo - M); xm = M;
                }
                {
                    float mo = ms_m(v3), so = ms_s(v3);
                    float M = fmaxf(xm, mo);
                    xs = xs * __expf(xm - M) + so * __expf(mo - M); xm = M;
                }
#pragma unroll
                for (int k = 1; k < 64; k <<= 1) {
                    float mo = __shfl_xor(xm, k, 64);
                    float so = __shfl_xor(xs, k, 64);
                    float M = fmaxf(xm, mo);
                    xs = xs * __expf(xm - M) + so * __expf(mo - M);
                    xm = M;
                }
                if (lane == 0) {
                    float xv = -__logf(xs);
                    xshare = xv;
                    if (b == 0) out[t - 1] = xv;
                }
            } else if (lane == 0) {
                xshare = 0.f;
            }
        }
        __syncthreads();
        const float x = xshare;

        // (3) v = LeakyReLU(intoW*x + intoB) -> LDS as f16 pairs
        {
            float v0 = fmaf(iw4.x, x, ib4.x); v0 = (v0 > 0.f) ? v0 : 0.01f * v0;
            float v1 = fmaf(iw4.y, x, ib4.y); v1 = (v1 > 0.f) ? v1 : 0.01f * v1;
            float v2 = fmaf(iw4.z, x, ib4.z); v2 = (v2 > 0.f) ? v2 : 0.01f * v2;
            float v3 = fmaf(iw4.w, x, ib4.w); v3 = (v3 > 0.f) ? v3 : 0.01f * v3;
            v16[2 * tid]     = pkh2(v0, v1);
            v16[2 * tid + 1] = pkh2(v2, v3);
        }
        __syncthreads();

        // (4) gx = Wih @ v; combine -> h(t+1)[i]; stage to LDS
        {
            float axr = 0.f, axz = 0.f, axn = 0.f;
#pragma unroll
            for (int it = 0; it < 4; ++it) {
                const uint4 vq = *(const uint4*)(v16 + it * 256 + lane * 4);
                axr = dot8(wXr[it], vq, axr);
                axz = dot8(wXz[it], vq, axz);
                axn = dot8(wXn[it], vq, axn);
            }
#pragma unroll
            for (int m = 1; m < 64; m <<= 1) {
                axr += __shfl_xor(axr, m, 64);
                axz += __shfl_xor(axz, m, 64);
                axn += __shfl_xor(axn, m, 64);
            }
            float r = 1.f / (1.f + __expf(-(axr + bxr + ahr + bhr)));
            float z = 1.f / (1.f + __expf(-(axz + bxz + ahz + bhz)));
            float n = tanhf(axn + bxn + r * (ahn + bhn));
            float hn = (1.f - z) * n + z * hold;
            hold = hn;                        // keep own h exact for next step
            if (lane == 0) h_sh[w] = hn;
        }
        __syncthreads();

        // (4b) publish tagged h pairs (4 per block) -- the store IS the arrival
        if (tid < 4) {
            uint32 pr = pkh2(h_sh[2 * tid], h_sh[2 * tid + 1]);
            gstore64(hpk + b * 4 + tid, (uint64)pr | ((uint64)eph << 32));
        }

        // (5)+(6) h-sync: consume ONLY after the release gate (R12 discipline)
        if (b == 0) {
            if (tid < 64) {   // aggregator wave: poll all 1024 words, release, fill h16
                uint64 va[16];
#pragma unroll
                for (int k = 0; k < 16; ++k) va[k] = gload64(hpk + tid + k * 64);
#pragma unroll
                for (int k = 0; k < 16; ++k)
                    while (pk_ep(va[k]) < eph) { __builtin_amdgcn_s_sleep(0); va[k] = gload64(hpk + tid + k * 64); }
                if (tid < 8) gstore(go + tid * BSTR, eph);
#pragma unroll
                for (int k = 0; k < 16; ++k) h16[tid + k * 64] = (uint32)va[k];
            }
            __syncthreads();
        } else {
            if (tid == 0) {
                const uint32* g = go + (b & 7) * BSTR;
                while (gload(g) < eph) __builtin_amdgcn_s_sleep(0);
            }
            __syncthreads();   // go seen: all tags >= eph at MALL
            uint64 p0 = gload64(hpk + tid);
            uint64 p1 = gload64(hpk + tid + 512);
            h16[tid]       = (uint32)p0;
            h16[tid + 512] = (uint32)p1;
            __syncthreads();
        }

        // (7) logits partials on h(t+1) (f16 wO); publish packed tag t+1
        {
            const int jbp = (w & 1) * 512;   // pair offset
            float acc = 0.f;
#pragma unroll
            for (int it = 0; it < 2; ++it) {
                const uint4 hq = *(const uint4*)(h16 + jbp + it * 256 + lane * 4);
                acc = dot8(wO[it], hq, acc);
            }
#pragma unroll
            for (int m = 1; m < 64; m <<= 1) acc += __shfl_xor(acc, m, 64);
            if (lane == 0) red_a[w] = acc;
            __syncthreads();
            if (tid == 0) {
                float l0 = red_a[0] + red_a[1] + ob0;
                float l1 = red_a[2] + red_a[3] + ob1;
                float l2 = red_a[4] + red_a[5] + ob2;
                float l3 = red_a[6] + red_a[7] + ob3;
                float m = fmaxf(fmaxf(l0, l1), fmaxf(l2, l3));
                float s = __expf(l0 - m) + __expf(l1 - m) + __expf(l2 - m) + __expf(l3 - m);
                gstore64(pm + b, pack_ms(m, s, (uint32)(t + 1)));
            }
        }
        // no loop-end sync: (5)/(6) syncs already order red_a/v16/xshare reuse
    }

    // epilogue: out[Os-1] from the last published partials (tag Os)
    if (b == 0 && w == 0) {
        float xm = -1e30f, xs = 0.f;
#pragma unroll
        for (int q = 0; q < 4; ++q) {
            uint64 v = spin_ms(pm + lane + q * 64, (uint32)Os);
            float mo = ms_m(v), so = ms_s(v);
            float M = fmaxf(xm, mo);
            xs = xs * __expf(xm - M) + so * __expf(mo - M);
            xm = M;
        }
#pragma unroll
        for (int k = 1; k < 64; k <<= 1) {
            float mo = __shfl_xor(xm, k, 64);
            float so = __shfl_xor(xs, k, 64);
            float M = fmaxf(xm, mo);
            xs = xs * __expf(xm - M) + so * __expf(mo - M);
            xm = M;
        }
        if (lane == 0) out[Os - 1] = -__logf(xs);
    }
}

extern "C" void kernel_launch(void* const* d_in, const int* in_sizes, int n_in,
                              void* d_out, int out_size, void* d_ws, size_t ws_size,
                              hipStream_t stream) {
    const float* a      = (const float*)d_in[0];
    const float* encWih = (const float*)d_in[1];
    // d_in[2] enc_Whh unused (h0 = 0)
    const float* encBih = (const float*)d_in[3];
    const float* encBhh = (const float*)d_in[4];
    const float* intoW  = (const float*)d_in[5];
    const float* intoB  = (const float*)d_in[6];
    const float* decWih = (const float*)d_in[7];
    const float* decWhh = (const float*)d_in[8];
    const float* decBih = (const float*)d_in[9];
    const float* decBhh = (const float*)d_in[10];
    const float* outW   = (const float*)d_in[11];
    const float* outB   = (const float*)d_in[12];

    ushort_t* wsWih  = (ushort_t*)d_ws;
    ushort_t* wsWhh  = wsWih + (size_t)3 * Hs * Hs;
    ushort_t* wsWout = wsWhh + (size_t)3 * Hs * Hs;
    uint64*   hpk    = (uint64*)(wsWout + (size_t)Os * Hs);
    uint64*   pmw    = hpk + Hs / 2;
    uint32*   gow    = (uint32*)(pmw + NB);
    float*    out    = (float*)d_out;

    cvt_kernel<<<4096, 256, 0, stream>>>(decWih, wsWih, 3 * Hs * Hs / 4);
    cvt_kernel<<<4096, 256, 0, stream>>>(decWhh, wsWhh, 3 * Hs * Hs / 4);
    cvt_kernel<<<1024, 256, 0, stream>>>(outW,  wsWout, Os * Hs / 4);
    // reset all epoch-tagged words + go words (contiguous)
    hipMemsetAsync(hpk, 0, (Hs / 2 + NB) * sizeof(uint64) + 8 * BSTR * sizeof(uint32), stream);

    void* args[] = {
        (void*)&a, (void*)&encWih, (void*)&encBih, (void*)&encBhh,
        (void*)&intoW, (void*)&intoB, (void*)&decBih, (void*)&decBhh,
        (void*)&outB, (void*)&wsWih, (void*)&wsWhh, (void*)&wsWout,
        (void*)&hpk, (void*)&pmw, (void*)&gow, (void*)&out
    };
    hipLaunchCooperativeKernel(reinterpret_cast<void*>(decode_kernel),
                               dim3(NB), dim3(NT), args, 0, stream);
}